// Round 2
// baseline (1071.687 us; speedup 1.0000x reference)
//
#include <hip/hip_runtime.h>
#include <hip/hip_bf16.h>

// HardMemory: x[32,512,64,64] f32, memory[1024,512] f32.
// sim = cos(x_pixel, mem_row); out[b,c,n] = memory[argmax][c] * (max>0.8)
// Pipeline: (1) normalize memory -> bf16, (2) MFMA GEMM + fused max/argmax,
// (3) branchless masked gather epilogue with NT stores.

typedef __attribute__((ext_vector_type(8))) short short8;   // 8 bf16 (4 VGPRs)
typedef __attribute__((ext_vector_type(4))) float f32x4;
typedef __attribute__((ext_vector_type(4))) int   i32x4;

#define THRESH 0.8f
#define EPSN   1e-12f

__device__ __forceinline__ short f2bf(float f) {
    union { float f; unsigned u; } v; v.f = f;
    unsigned r = v.u + 0x7fffu + ((v.u >> 16) & 1u);   // RNE
    return (short)(r >> 16);
}

// ---------------- kernel 1: normalize memory rows -> bf16 ----------------
__global__ __launch_bounds__(256) void norm_mem_kernel(
        const float* __restrict__ mem, short* __restrict__ mem_bf) {
    const int row = blockIdx.x;          // 1024
    const int t   = threadIdx.x;         // 256
    const float* r = mem + (size_t)row * 512;
    float v0 = r[t], v1 = r[t + 256];
    float ss = v0 * v0 + v1 * v1;
    #pragma unroll
    for (int off = 32; off; off >>= 1) ss += __shfl_down(ss, off, 64);
    __shared__ float part[4];
    __shared__ float rinv_s;
    if ((t & 63) == 0) part[t >> 6] = ss;
    __syncthreads();
    if (t == 0) {
        float s = part[0] + part[1] + part[2] + part[3];
        rinv_s = 1.0f / fmaxf(sqrtf(s), EPSN);
    }
    __syncthreads();
    float rinv = rinv_s;
    mem_bf[(size_t)row * 512 + t]       = f2bf(v0 * rinv);
    mem_bf[(size_t)row * 512 + t + 256] = f2bf(v1 * rinv);
}

// ---------------- kernel 2: GEMM + fused row max/argmax ----------------
// Block: 64 pixels x all 1024 mems. 512 threads = 8 waves in 2(pixel)x4(mem).
// Wave tile: 32 pixels x 64 mems -> 8 mfma_f32_16x16x32_bf16 per K-step of 32,
// against 2 LDS A-reads + 4 global B-reads (B is L2-resident, 1 MiB).
// 1-step B prefetch; launch_bounds(512,4) -> 128 VGPR, 2 blocks/CU, 16 waves/CU.
__global__ __launch_bounds__(512, 4) void simmax_kernel(
        const float* __restrict__ x, const short* __restrict__ memn,
        int* __restrict__ selv) {
    __shared__ short xs[64 * 512];       // 64 KiB, A-tile pre-fragmented
    __shared__ float part[8][64];        // per-wave partial ||x||^2
    __shared__ float redv[4][64];        // per-wm max
    __shared__ int   redi[4][64];        // per-wm argmax

    const int t  = threadIdx.x;          // 0..511
    const int b  = blockIdx.y;           // 32
    const int n0 = blockIdx.x * 64;      // 64 pixel tiles
    const int p  = t & 63;
    const int w  = t >> 6;               // wave 0..7

    // ---- stage X tile: x[b, c, n0+p] -> xs[(c/8)*64 + p][c%8] as bf16 ----
    // fp32 sum-of-squares accumulated on the fly (matches reference norm).
    const float* xb = x + ((size_t)b * 512) * 4096 + n0 + p;
    float ss = 0.f;
    for (int oct = w; oct < 64; oct += 8) {
        short8 pk;
        #pragma unroll
        for (int i = 0; i < 8; ++i) {
            float v = xb[(size_t)(oct * 8 + i) * 4096];
            ss += v * v;
            pk[i] = f2bf(v);
        }
        *(short8*)&xs[(oct * 64 + p) * 8] = pk;
    }
    part[w][p] = ss;
    __syncthreads();

    float xnorm_reg = 1.0f;
    if (t < 64) {
        float s = 0.f;
        #pragma unroll
        for (int j = 0; j < 8; ++j) s += part[j][t];
        xnorm_reg = fmaxf(sqrtf(s), EPSN);
    }

    const int lane = t & 63;
    const int quad = lane >> 4;
    const int l15  = lane & 15;
    const int wp   = w & 1;              // pixel half (0/1)
    const int wm   = w >> 1;             // mem quarter (0..3)
    const int pa0  = wp * 32 + l15;

    float runv[2][4];
    int   runi[2][4];
    #pragma unroll
    for (int i = 0; i < 2; ++i)
        #pragma unroll
        for (int r = 0; r < 4; ++r) { runv[i][r] = -1e30f; runi[i][r] = 0; }

    for (int mc = 0; mc < 4; ++mc) {
        f32x4 acc[2][4];
        #pragma unroll
        for (int i = 0; i < 2; ++i)
            #pragma unroll
            for (int j = 0; j < 4; ++j) acc[i][j] = (f32x4){0.f, 0.f, 0.f, 0.f};

        const int mb = mc * 256 + wm * 64;
        const short* bptr = memn + (size_t)(mb + l15) * 512 + quad * 8;

        short8 bcur[4];
        #pragma unroll
        for (int j = 0; j < 4; ++j)
            bcur[j] = *(const short8*)(bptr + j * 8192);   // rows j*16 apart

        #pragma unroll
        for (int kk = 0; kk < 512; kk += 32) {
            short8 bnxt[4];
            if (kk + 32 < 512) {
                #pragma unroll
                for (int j = 0; j < 4; ++j)
                    bnxt[j] = *(const short8*)(bptr + j * 8192 + kk + 32);
            }
            const int oct = (kk >> 3) + quad;
            short8 a0 = *(const short8*)&xs[(oct * 64 + pa0) * 8];
            short8 a1 = *(const short8*)&xs[(oct * 64 + pa0 + 16) * 8];
            #pragma unroll
            for (int j = 0; j < 4; ++j) {
                acc[0][j] = __builtin_amdgcn_mfma_f32_16x16x32_bf16(a0, bcur[j], acc[0][j], 0, 0, 0);
                acc[1][j] = __builtin_amdgcn_mfma_f32_16x16x32_bf16(a1, bcur[j], acc[1][j], 0, 0, 0);
            }
            if (kk + 32 < 512) {
                #pragma unroll
                for (int j = 0; j < 4; ++j) bcur[j] = bnxt[j];
            }
        }

        #pragma unroll
        for (int i = 0; i < 2; ++i)
            #pragma unroll
            for (int j = 0; j < 4; ++j) {        // ascending col -> first-max tie-break
                const int cb = mb + j * 16 + l15;
                #pragma unroll
                for (int r = 0; r < 4; ++r) {
                    float v = acc[i][j][r];
                    if (v > runv[i][r]) { runv[i][r] = v; runi[i][r] = cb; }
                }
            }
    }

    // ---- cross-lane max/argmax (cols live on the 16 lanes of each quad) ----
    #pragma unroll
    for (int i = 0; i < 2; ++i)
        #pragma unroll
        for (int r = 0; r < 4; ++r) {
            float v = runv[i][r]; int ix = runi[i][r];
            #pragma unroll
            for (int off = 1; off < 16; off <<= 1) {
                float ov = __shfl_xor(v, off, 64);
                int   oi = __shfl_xor(ix, off, 64);
                if (ov > v || (ov == v && oi < ix)) { v = ov; ix = oi; }
            }
            if (l15 == 0) {
                const int pl = wp * 32 + i * 16 + quad * 4 + r;  // pixel row
                redv[wm][pl] = v;
                redi[wm][pl] = ix;
            }
        }

    __syncthreads();
    if (t < 64) {
        float v = redv[0][t]; int ix = redi[0][t];
        #pragma unroll
        for (int c = 1; c < 4; ++c) {            // ascending mem chunks
            float ov = redv[c][t]; int oi = redi[c][t];
            if (ov > v || (ov == v && oi < ix)) { v = ov; ix = oi; }
        }
        float maxval = v / xnorm_reg;
        selv[(size_t)b * 4096 + n0 + t] = (maxval > THRESH) ? ix : -1;
    }
}

// ---------------- kernel 3: branchless masked gather -> transposed out ----------------
// out[b, c, n] = sel[b,n] >= 0 ? memory[sel][c] : 0   (clamp row, multiply mask)
__global__ __launch_bounds__(256) void scatter_kernel(
        const float* __restrict__ mem, const int* __restrict__ selv,
        float* __restrict__ out) {
    const int t  = threadIdx.x;          // 256
    const int nt = blockIdx.x;           // 4
    const int b  = blockIdx.y;           // 32
    const int cs = blockIdx.z;           // 8   (64 c per block)
    const int n  = nt * 1024 + t * 4;
    i32x4 sel = *(const i32x4*)&selv[(size_t)b * 4096 + n];
    const int c0 = cs * 64;
    const float* r0 = mem + (size_t)(sel.x < 0 ? 0 : sel.x) * 512 + c0;
    const float* r1 = mem + (size_t)(sel.y < 0 ? 0 : sel.y) * 512 + c0;
    const float* r2 = mem + (size_t)(sel.z < 0 ? 0 : sel.z) * 512 + c0;
    const float* r3 = mem + (size_t)(sel.w < 0 ? 0 : sel.w) * 512 + c0;
    const float m0 = (sel.x < 0) ? 0.f : 1.f;
    const float m1 = (sel.y < 0) ? 0.f : 1.f;
    const float m2 = (sel.z < 0) ? 0.f : 1.f;
    const float m3 = (sel.w < 0) ? 0.f : 1.f;
    float* ob = out + ((size_t)b * 512 + c0) * 4096 + n;
    #pragma unroll 4
    for (int c = 0; c < 64; ++c) {
        f32x4 v;
        v.x = m0 * r0[c];
        v.y = m1 * r1[c];
        v.z = m2 * r2[c];
        v.w = m3 * r3[c];
        __builtin_nontemporal_store(v, (f32x4*)&ob[(size_t)c * 4096]);
    }
}

extern "C" void kernel_launch(void* const* d_in, const int* in_sizes, int n_in,
                              void* d_out, int out_size, void* d_ws, size_t ws_size,
                              hipStream_t stream) {
    const float* x   = (const float*)d_in[0];   // [32,512,64,64]
    const float* mem = (const float*)d_in[1];   // [1024,512]
    short* mem_bf = (short*)d_ws;                       // 1 MiB bf16 normalized
    int*   selv   = (int*)((char*)d_ws + (1 << 20));    // 512 KiB selections
    float* out    = (float*)d_out;

    norm_mem_kernel<<<dim3(1024), dim3(256), 0, stream>>>(mem, mem_bf);
    simmax_kernel<<<dim3(64, 32), dim3(512), 0, stream>>>(x, mem_bf, selv);
    scatter_kernel<<<dim3(4, 32, 8), dim3(256), 0, stream>>>(mem, selv, out);
}

// Round 3
// 914.962 us; speedup vs baseline: 1.1713x; 1.1713x over previous
//
#include <hip/hip_runtime.h>
#include <hip/hip_bf16.h>

// HardMemory: x[32,512,64,64] f32, memory[1024,512] f32.
// sim = cos(x_pixel, mem_row); out[b,c,n] = memory[argmax][c] * (max>0.8)
// Pipeline: (1) normalize memory -> bf16, (2) MFMA GEMM + fused max/argmax,
// (3) masked gather epilogue, wave-sequential stores.

typedef __attribute__((ext_vector_type(8))) short short8;   // 8 bf16 (4 VGPRs)
typedef __attribute__((ext_vector_type(4))) float f32x4;
typedef __attribute__((ext_vector_type(4))) int   i32x4;

#define THRESH 0.8f
#define EPSN   1e-12f

__device__ __forceinline__ short f2bf(float f) {
    union { float f; unsigned u; } v; v.f = f;
    unsigned r = v.u + 0x7fffu + ((v.u >> 16) & 1u);   // RNE
    return (short)(r >> 16);
}

// ---------------- kernel 1: normalize memory rows -> bf16 ----------------
__global__ __launch_bounds__(256) void norm_mem_kernel(
        const float* __restrict__ mem, short* __restrict__ mem_bf) {
    const int row = blockIdx.x;          // 1024
    const int t   = threadIdx.x;         // 256
    const float* r = mem + (size_t)row * 512;
    float v0 = r[t], v1 = r[t + 256];
    float ss = v0 * v0 + v1 * v1;
    #pragma unroll
    for (int off = 32; off; off >>= 1) ss += __shfl_down(ss, off, 64);
    __shared__ float part[4];
    __shared__ float rinv_s;
    if ((t & 63) == 0) part[t >> 6] = ss;
    __syncthreads();
    if (t == 0) {
        float s = part[0] + part[1] + part[2] + part[3];
        rinv_s = 1.0f / fmaxf(sqrtf(s), EPSN);
    }
    __syncthreads();
    float rinv = rinv_s;
    mem_bf[(size_t)row * 512 + t]       = f2bf(v0 * rinv);
    mem_bf[(size_t)row * 512 + t + 256] = f2bf(v1 * rinv);
}

// ---------------- kernel 2: GEMM + fused row max/argmax ----------------
// Block: 64 pixels x all 1024 mems. 256 threads = 4 waves.
// Wave tile: 64 pixels x 64 mems -> 16 mfma_f32_16x16x32_bf16 per K-step,
// per K-step: 4 LDS A-reads + 4 global B-reads (prefetched 1 step ahead).
// Waves split mems (each B row fetched once/block). mc loop: 4 x 256 mems.
// launch_bounds(256,2): VGPR budget 256 (~200 used, NO spill), LDS 67 KiB
// -> 2 blocks/CU = 8 waves/CU.
__global__ __launch_bounds__(256, 2) void simmax_kernel(
        const float* __restrict__ x, const short* __restrict__ memn,
        int* __restrict__ selv) {
    __shared__ short xs[64 * 512];       // 64 KiB, A-tile pre-fragmented
    __shared__ float part[4][64];        // per-wave partial ||x||^2
    __shared__ float redv[4][64];        // per-wave max
    __shared__ int   redi[4][64];        // per-wave argmax

    const int t  = threadIdx.x;          // 0..255
    const int b  = blockIdx.y;           // 32
    const int n0 = blockIdx.x * 64;      // 64 pixel tiles
    const int p  = t & 63;
    const int w  = t >> 6;               // wave 0..3

    // ---- stage X tile: x[b, c, n0+p] -> xs[(c/8)*64 + p][c%8] as bf16 ----
    const float* xb = x + ((size_t)b * 512) * 4096 + n0 + p;
    float ss = 0.f;
    for (int oct = w; oct < 64; oct += 4) {
        short8 pk;
        #pragma unroll
        for (int i = 0; i < 8; ++i) {
            float v = xb[(size_t)(oct * 8 + i) * 4096];
            ss += v * v;
            pk[i] = f2bf(v);
        }
        *(short8*)&xs[(oct * 64 + p) * 8] = pk;
    }
    part[w][p] = ss;
    __syncthreads();

    float xnorm_reg = 1.0f;
    if (t < 64) {
        float s = part[0][t] + part[1][t] + part[2][t] + part[3][t];
        xnorm_reg = fmaxf(sqrtf(s), EPSN);
    }

    const int lane = t & 63;
    const int quad = lane >> 4;
    const int l15  = lane & 15;

    float runv[4][4];
    int   runi[4][4];
    #pragma unroll
    for (int i = 0; i < 4; ++i)
        #pragma unroll
        for (int r = 0; r < 4; ++r) { runv[i][r] = -1e30f; runi[i][r] = 0; }

    for (int mc = 0; mc < 4; ++mc) {
        f32x4 acc[4][4];
        #pragma unroll
        for (int i = 0; i < 4; ++i)
            #pragma unroll
            for (int j = 0; j < 4; ++j) acc[i][j] = (f32x4){0.f, 0.f, 0.f, 0.f};

        const int mb = mc * 256 + w * 64;          // this wave's 64 mems
        const short* bptr = memn + (size_t)(mb + l15) * 512 + quad * 8;

        short8 bcur[4];
        #pragma unroll
        for (int j = 0; j < 4; ++j)
            bcur[j] = *(const short8*)(bptr + j * 8192);   // rows j*16 apart

        #pragma unroll
        for (int kk = 0; kk < 512; kk += 32) {
            short8 bnxt[4];
            if (kk + 32 < 512) {
                #pragma unroll
                for (int j = 0; j < 4; ++j)
                    bnxt[j] = *(const short8*)(bptr + j * 8192 + kk + 32);
            }
            const int oct = (kk >> 3) + quad;
            short8 a[4];
            #pragma unroll
            for (int i = 0; i < 4; ++i)
                a[i] = *(const short8*)&xs[(oct * 64 + i * 16 + l15) * 8];
            #pragma unroll
            for (int i = 0; i < 4; ++i)
                #pragma unroll
                for (int j = 0; j < 4; ++j)
                    acc[i][j] = __builtin_amdgcn_mfma_f32_16x16x32_bf16(
                        a[i], bcur[j], acc[i][j], 0, 0, 0);
            if (kk + 32 < 512) {
                #pragma unroll
                for (int j = 0; j < 4; ++j) bcur[j] = bnxt[j];
            }
        }

        #pragma unroll
        for (int i = 0; i < 4; ++i)
            #pragma unroll
            for (int j = 0; j < 4; ++j) {        // ascending col within wave
                const int cb = mb + j * 16 + l15;
                #pragma unroll
                for (int r = 0; r < 4; ++r) {
                    float v = acc[i][j][r];
                    if (v > runv[i][r]) { runv[i][r] = v; runi[i][r] = cb; }
                }
            }
    }

    // ---- cross-lane max/argmax (cols live on 16 lanes of each quad) ----
    #pragma unroll
    for (int i = 0; i < 4; ++i)
        #pragma unroll
        for (int r = 0; r < 4; ++r) {
            float v = runv[i][r]; int ix = runi[i][r];
            #pragma unroll
            for (int off = 1; off < 16; off <<= 1) {
                float ov = __shfl_xor(v, off, 64);
                int   oi = __shfl_xor(ix, off, 64);
                if (ov > v || (ov == v && oi < ix)) { v = ov; ix = oi; }
            }
            if (l15 == 0) {
                const int pl = i * 16 + quad * 4 + r;   // pixel row 0..63
                redv[w][pl] = v;
                redi[w][pl] = ix;
            }
        }

    __syncthreads();
    if (t < 64) {
        float v = redv[0][t]; int ix = redi[0][t];
        #pragma unroll
        for (int c = 1; c < 4; ++c) {            // index-based tie-break
            float ov = redv[c][t]; int oi = redi[c][t];
            if (ov > v || (ov == v && oi < ix)) { v = ov; ix = oi; }
        }
        float maxval = v / xnorm_reg;
        selv[(size_t)b * 4096 + n0 + t] = (maxval > THRESH) ? ix : -1;
    }
}

// ---------------- kernel 3: masked gather, wave-sequential stores ----------------
// Each wave owns one contiguous output row out[b, c, 0..4096) = 16 KiB and
// streams it: dense instantaneous write footprint (page-friendly).
__global__ __launch_bounds__(256) void scatter_kernel(
        const float* __restrict__ mem, const int* __restrict__ selv,
        float* __restrict__ out) {
    const int t    = threadIdx.x;        // 256
    const int w    = t >> 6;             // wave 0..3
    const int lane = t & 63;
    const int cg   = blockIdx.x;         // 128 groups of 4 c
    const int b    = blockIdx.y;         // 32
    const int c    = cg * 4 + w;         // this wave's channel
    const int* sb  = selv + (size_t)b * 4096;
    const float* mc_ = mem + c;
    float* ob = out + ((size_t)b * 512 + c) * 4096;
    #pragma unroll
    for (int rd = 0; rd < 16; ++rd) {
        const int n = rd * 256 + lane * 4;
        i32x4 sel = *(const i32x4*)&sb[n];
        f32x4 v;
        v.x = (sel.x < 0) ? 0.f : mc_[(size_t)sel.x * 512];
        v.y = (sel.y < 0) ? 0.f : mc_[(size_t)sel.y * 512];
        v.z = (sel.z < 0) ? 0.f : mc_[(size_t)sel.z * 512];
        v.w = (sel.w < 0) ? 0.f : mc_[(size_t)sel.w * 512];
        __builtin_nontemporal_store(v, (f32x4*)&ob[n]);
    }
}

extern "C" void kernel_launch(void* const* d_in, const int* in_sizes, int n_in,
                              void* d_out, int out_size, void* d_ws, size_t ws_size,
                              hipStream_t stream) {
    const float* x   = (const float*)d_in[0];   // [32,512,64,64]
    const float* mem = (const float*)d_in[1];   // [1024,512]
    short* mem_bf = (short*)d_ws;                       // 1 MiB bf16 normalized
    int*   selv   = (int*)((char*)d_ws + (1 << 20));    // 512 KiB selections
    float* out    = (float*)d_out;

    norm_mem_kernel<<<dim3(1024), dim3(256), 0, stream>>>(mem, mem_bf);
    simmax_kernel<<<dim3(64, 32), dim3(256), 0, stream>>>(x, mem_bf, selv);
    scatter_kernel<<<dim3(128, 32), dim3(256), 0, stream>>>(mem, selv, out);
}